// Round 1
// baseline (32.167 us; speedup 1.0000x reference)
//
#include <hip/hip_runtime.h>
#include <math.h>

#define EARLY 1.5f
#define GAP   3.0f
#define LATE  2.0f

#define NBLOCKS 2048
#define NTHREADS 256

__device__ __forceinline__ float term(float a, float b) {
    float d = b - a;
    float w = (d >= GAP) ? EARLY : ((d < 0.0f) ? LATE : 1.0f);
    float t = d * w;
    return t * t;
}

__global__ __launch_bounds__(NTHREADS) void rmse_partial_kernel(
    const float* __restrict__ in, const float* __restrict__ tg,
    float* __restrict__ partial, int n)
{
    const int n4 = n >> 2;  // number of float4 chunks
    const float4* __restrict__ in4 = (const float4*)in;
    const float4* __restrict__ tg4 = (const float4*)tg;

    float acc = 0.0f;
    int idx = blockIdx.x * blockDim.x + threadIdx.x;
    int stride = gridDim.x * blockDim.x;

    for (int i = idx; i < n4; i += stride) {
        float4 a = in4[i];
        float4 b = tg4[i];
        acc += term(a.x, b.x);
        acc += term(a.y, b.y);
        acc += term(a.z, b.z);
        acc += term(a.w, b.w);
    }
    // scalar tail (n not divisible by 4)
    for (int i = (n4 << 2) + idx; i < n; i += stride) {
        acc += term(in[i], tg[i]);
    }

    // wave-64 reduction
    #pragma unroll
    for (int off = 32; off > 0; off >>= 1)
        acc += __shfl_down(acc, off, 64);

    __shared__ float smem[NTHREADS / 64];
    int lane = threadIdx.x & 63;
    int wid  = threadIdx.x >> 6;
    if (lane == 0) smem[wid] = acc;
    __syncthreads();

    if (threadIdx.x == 0) {
        float t = 0.0f;
        #pragma unroll
        for (int w = 0; w < NTHREADS / 64; ++w) t += smem[w];
        partial[blockIdx.x] = t;
    }
}

__global__ __launch_bounds__(NTHREADS) void rmse_final_kernel(
    const float* __restrict__ partial, int nb,
    float* __restrict__ out, float invN)
{
    float acc = 0.0f;
    for (int i = threadIdx.x; i < nb; i += blockDim.x)
        acc += partial[i];

    #pragma unroll
    for (int off = 32; off > 0; off >>= 1)
        acc += __shfl_down(acc, off, 64);

    __shared__ float smem[NTHREADS / 64];
    int lane = threadIdx.x & 63;
    int wid  = threadIdx.x >> 6;
    if (lane == 0) smem[wid] = acc;
    __syncthreads();

    if (threadIdx.x == 0) {
        float t = 0.0f;
        #pragma unroll
        for (int w = 0; w < NTHREADS / 64; ++w) t += smem[w];
        out[0] = sqrtf(t * invN);
    }
}

extern "C" void kernel_launch(void* const* d_in, const int* in_sizes, int n_in,
                              void* d_out, int out_size, void* d_ws, size_t ws_size,
                              hipStream_t stream) {
    const float* inputs  = (const float*)d_in[0];
    const float* targets = (const float*)d_in[1];
    float* out = (float*)d_out;
    float* partial = (float*)d_ws;   // NBLOCKS floats, well under ws_size
    int n = in_sizes[0];

    rmse_partial_kernel<<<NBLOCKS, NTHREADS, 0, stream>>>(inputs, targets, partial, n);
    rmse_final_kernel<<<1, NTHREADS, 0, stream>>>(partial, NBLOCKS, out, 1.0f / (float)n);
}